// Round 7
// baseline (4532.769 us; speedup 1.0000x reference)
//
#include <hip/hip_runtime.h>
#include <cstddef>
#include <cstdint>

namespace {

constexpr int kB  = 4096;   // batch
constexpr int kIN = 4096;
constexpr int kFS = 4096;
constexpr int kS  = 64;
constexpr int kH  = 512;
constexpr int kNG = 2048;   // 4*H
constexpr int kKC = 576;    // 64 (input slice) + 512 (hidden)

typedef __bf16 bf16_t;
typedef __bf16 bfrag  __attribute__((ext_vector_type(8)));
typedef __bf16 bf16v4 __attribute__((ext_vector_type(4)));
typedef float  f32x4  __attribute__((ext_vector_type(4)));

__device__ __forceinline__ void gload16(const void* g, void* l) {
  __builtin_amdgcn_global_load_lds(
      (const __attribute__((address_space(1))) void*)g,
      (__attribute__((address_space(3))) void*)l, 16, 0, 0);
}

__device__ __forceinline__ float sigf(float x) { return 1.0f / (1.0f + __expf(-x)); }
__device__ __forceinline__ float tanh_fast(float x) {
  float e = __expf(2.0f * x);
  return 1.0f - 2.0f / (e + 1.0f);
}

__device__ __forceinline__ f32x4 mfma16(bfrag a, bfrag b, f32x4 c) {
  return __builtin_amdgcn_mfma_f32_16x16x32_bf16(a, b, c, 0, 0, 0);
}

__device__ __forceinline__ void vwait(int n) {
  if (n == 6)      asm volatile("s_waitcnt vmcnt(6)" ::: "memory");
  else if (n == 4) asm volatile("s_waitcnt vmcnt(4)" ::: "memory");
  else if (n == 2) asm volatile("s_waitcnt vmcnt(2)" ::: "memory");
  else             asm volatile("s_waitcnt vmcnt(0)" ::: "memory");
  __builtin_amdgcn_sched_barrier(0);
}

// ---------------- pack kernels (unchanged) ----------------

__global__ __launch_bounds__(256) void f2b4_kernel(const float* __restrict__ in,
                                                   bf16_t* __restrict__ out, int n4) {
  int i = blockIdx.x * 256 + threadIdx.x;
  if (i >= n4) return;
  float4 v = reinterpret_cast<const float4*>(in)[i];
  bf16v4 o = {(bf16_t)v.x, (bf16_t)v.y, (bf16_t)v.z, (bf16_t)v.w};
  *reinterpret_cast<bf16v4*>(out + (size_t)i * 4) = o;
}

__global__ __launch_bounds__(256) void pack_wcat_kernel(
    const float* __restrict__ Wih_l, const float* __restrict__ Whh_l,
    const float* __restrict__ Wih_r, const float* __restrict__ Whh_r,
    const float* __restrict__ Wih_d, const float* __restrict__ Whh_d,
    bf16_t* __restrict__ wcat) {
  int idx = blockIdx.x * 256 + threadIdx.x;
  if (idx >= 3 * kNG * kKC) return;
  int m = idx / (kNG * kKC);
  int rem = idx - m * (kNG * kKC);
  int rr = rem / kKC;
  int k  = rem - rr * kKC;
  int u = rr >> 2, g = rr & 3;
  int orow = g * kH + u;
  const float* Wih = (m == 0) ? Wih_l : (m == 1) ? Wih_r : Wih_d;
  const float* Whh = (m == 0) ? Whh_l : (m == 1) ? Whh_r : Whh_d;
  float v = (k < 64) ? Wih[(size_t)orow * 64 + k] : Whh[(size_t)orow * 512 + (k - 64)];
  wcat[idx] = (bf16_t)v;
}

__global__ __launch_bounds__(256) void pack_bias_kernel(
    const float* __restrict__ bih_l, const float* __restrict__ bhh_l,
    const float* __restrict__ bih_r, const float* __restrict__ bhh_r,
    const float* __restrict__ bih_d, const float* __restrict__ bhh_d,
    float* __restrict__ biasc) {
  int idx = blockIdx.x * 256 + threadIdx.x;
  if (idx >= 3 * kNG) return;
  int m = idx / kNG;
  int rr = idx - m * kNG;
  int u = rr >> 2, g = rr & 3;
  int orow = g * kH + u;
  const float* bi = (m == 0) ? bih_l : (m == 1) ? bih_r : bih_d;
  const float* bh = (m == 0) ? bhh_l : (m == 1) ? bhh_r : bhh_d;
  biasc[idx] = bi[orow] + bh[orow];
}

__global__ __launch_bounds__(256) void pack_hc_kernel(const float* __restrict__ h0,
                                                      const float* __restrict__ c0,
                                                      bf16_t* __restrict__ hbuf0,
                                                      float* __restrict__ cbuf, int n) {
  int i = blockIdx.x * 256 + threadIdx.x;
  if (i >= n) return;
  hbuf0[i] = (bf16_t)h0[i];
  cbuf[i]  = c0[i];
}

__global__ __launch_bounds__(256) void transpose64_kernel(const bf16_t* __restrict__ feat,
                                                          bf16_t* __restrict__ featT) {
  __shared__ bf16_t tile[64][65];
  const int b = blockIdx.x;
  const bf16_t* src = feat + (size_t)b * kFS;
  bf16_t* dst = featT + (size_t)b * kFS;
  for (int i = threadIdx.x; i < 4096; i += 256) tile[i >> 6][i & 63] = src[i];
  __syncthreads();
  for (int i = threadIdx.x; i < 4096; i += 256) dst[i] = tile[i & 63][i >> 6];
}

// ---------------- feat GEMM (unchanged) ----------------

__global__ __launch_bounds__(256, 4) void gemm_feat_kernel(
    const bf16_t* __restrict__ X, const bf16_t* __restrict__ W,
    const float* __restrict__ b1, bf16_t* __restrict__ feat) {
  __shared__ bf16_t As[128 * 32];
  __shared__ bf16_t Bs[128 * 32];
  const int t = threadIdx.x;
  const int bid = blockIdx.x;
  const int widx = (bid & 7) * 128 + (bid >> 3);
  const int bm = widx & 31, bn = widx >> 5;
  const int w = t >> 6, l = t & 63;
  const int wm = (w >> 1) * 64, wn = (w & 1) * 64;
  const int sr = t >> 2;
  const int skS = ((t & 3) ^ ((t >> 3) & 3)) * 8;
  const int lr = l & 15;
  const int lkS = ((l >> 4) ^ ((l >> 1) & 3)) * 8;
  const int lrow4 = (l >> 4) * 4;

  f32x4 acc[4][4];
#pragma unroll
  for (int i = 0; i < 4; ++i)
#pragma unroll
    for (int j = 0; j < 4; ++j) acc[i][j] = (f32x4){0.f, 0.f, 0.f, 0.f};

  const bf16_t* ga = X + (size_t)(bm * 128 + sr) * kIN + skS;
  const bf16_t* gb = W + (size_t)(bn * 128 + sr) * kIN + skS;
  bf16_t* lA = As + w * 512;
  bf16_t* lB = Bs + w * 512;

  for (int kt = 0; kt < kIN / 32; ++kt) {
    gload16(ga, lA);
    gload16(ga + (size_t)64 * kIN, lA + 2048);
    gload16(gb, lB);
    gload16(gb + (size_t)64 * kIN, lB + 2048);
    ga += 32; gb += 32;
    __syncthreads();
    bfrag a[4], b[4];
#pragma unroll
    for (int mi = 0; mi < 4; ++mi)
      a[mi] = *reinterpret_cast<const bfrag*>(&As[(wm + mi * 16 + lr) * 32 + lkS]);
#pragma unroll
    for (int ni = 0; ni < 4; ++ni)
      b[ni] = *reinterpret_cast<const bfrag*>(&Bs[(wn + ni * 16 + lr) * 32 + lkS]);
#pragma unroll
    for (int mi = 0; mi < 4; ++mi)
#pragma unroll
      for (int ni = 0; ni < 4; ++ni)
        acc[mi][ni] = __builtin_amdgcn_mfma_f32_16x16x32_bf16(a[mi], b[ni], acc[mi][ni], 0, 0, 0);
    __syncthreads();
  }

#pragma unroll
  for (int ni = 0; ni < 4; ++ni) {
    const int col = bn * 128 + wn + ni * 16 + lr;
    const float bb = b1[col];
#pragma unroll
    for (int mi = 0; mi < 4; ++mi) {
#pragma unroll
      for (int r = 0; r < 4; ++r) {
        const int row = bm * 128 + wm + mi * 16 + lrow4 + r;
        float v = acc[mi][ni][r] + bb;
        feat[(size_t)row * kFS + col] = (bf16_t)fmaxf(v, 0.0f);
      }
    }
  }
}

// ---------------- 256x256 step kernel with 1-phase register lookahead ----------------
// Quadrant order (aP*bP),(aP*bQ),(aQ*bP),(aQ*bQ): every phase's MFMA operands were
// ds_read in the PREVIOUS phase; this phase issues the next 4-8 ds_reads before its
// MFMA burst, so the LDS pipe executes under the MFMA burst (compiler emits counted
// lgkmcnt). Stage order per tile: B(t+1,r1), A(t+1,r1), A(t+2,r0), B(t+2,r0);
// vmcnt(6) at each phase end; tail: tile7 {6,6,4,2}, tile8 {0,..}. One barrier/phase.
// NOTE: no pointer arrays into LDS (runtime-indexed addrspace(3) pointer arrays
// trigger "static initializer" codegen errors) — bases computed arithmetically.

#define QUAD(A, B, MO, NO)                                              \
  _Pragma("unroll") for (int kk = 0; kk < 2; ++kk)                      \
  _Pragma("unroll") for (int mm = 0; mm < 4; ++mm)                      \
  _Pragma("unroll") for (int nn = 0; nn < 2; ++nn)                      \
      acc[(MO) + mm][(NO) + nn] =                                       \
          mfma16(A[mm * 2 + kk], B[nn * 2 + kk], acc[(MO) + mm][(NO) + nn]);

__global__ __launch_bounds__(512, 2) void lstm_step256_kernel(
    const bf16_t* __restrict__ feat, const bf16_t* __restrict__ featT,
    const bf16_t* __restrict__ wcat, const float* __restrict__ biasc,
    const bf16_t* __restrict__ hin, bf16_t* __restrict__ hout,
    float* __restrict__ cbuf, int s) {
  extern __shared__ __align__(16) char smem[];

  const int t = threadIdx.x;
  const int l = t & 63, w = t >> 6;
  const int wr = w >> 2, wc = w & 3;     // 2M x 4N wave grid; wave tile 128x64
  const int lr = l & 15, lq = l >> 4;
  const int sx = lr & 7;
  const int srow = l >> 3;
  const int sslot = (l & 7) ^ srow;      // pre-swizzled global 16B-slot

  const int bid = blockIdx.x;
  const int widx = (bid & 7) * 64 + (bid >> 3);   // XCD swizzle (512 % 8 == 0)
  const int cell = widx >> 7;
  const int rwk = widx & 127;
  const int bm = rwk >> 3, bn = rwk & 7;

  auto Abase = [&](int i) -> bf16_t* { return (bf16_t*)(smem + i * 65536); };
  auto Bbase = [&](int i) -> bf16_t* { return (bf16_t*)(smem + 32768 + i * 65536); };

  const bf16_t* xsrc = (cell < 2) ? feat : featT;
  const int off = ((cell & 1) ? (63 - s) : s) * 64;
  const int mat = (cell < 2) ? cell : 2;
  const bf16_t* Wm = wcat + (size_t)mat * kNG * kKC;
  const bf16_t* hc = hin + (size_t)cell * kB * kH;

  auto stage_A = [&](int kt, int buf, int ra) {
#pragma unroll
    for (int j = 0; j < 2; ++j) {
      const int row0 = ra * 64 + w * 8 + j * 128;   // wave-uniform
      bf16_t* dst = Abase(buf) + row0 * 64;
      const bf16_t* src = (kt == 0)
          ? xsrc + (size_t)(bm * 256 + row0 + srow) * kFS + off + sslot * 8
          : hc + (size_t)(bm * 256 + row0 + srow) * kH + (kt - 1) * 64 + sslot * 8;
      gload16(src, dst);
    }
  };
  auto stage_B = [&](int kt, int buf, int rb) {
#pragma unroll
    for (int j = 0; j < 2; ++j) {
      const int row0 = (w >> 2) * 64 + (w & 3) * 8 + rb * 32 + j * 128;
      bf16_t* dst = Bbase(buf) + row0 * 64;
      const bf16_t* src =
          Wm + (size_t)(bn * 256 + row0 + srow) * kKC + kt * 64 + sslot * 8;
      gload16(src, dst);
    }
  };

  f32x4 acc[8][4];
#pragma unroll
  for (int i = 0; i < 8; ++i)
#pragma unroll
    for (int j = 0; j < 4; ++j) acc[i][j] = (f32x4){0.f, 0.f, 0.f, 0.f};

  bfrag aP[8], aQ[8], bP[4], bQ[4];

  auto read_a = [&](bfrag (&d)[8], int buf, int mh) {
    const bf16_t* base = Abase(buf);
#pragma unroll
    for (int mm = 0; mm < 4; ++mm)
#pragma unroll
      for (int kk = 0; kk < 2; ++kk)
        d[mm * 2 + kk] = *reinterpret_cast<const bfrag*>(
            base + (wr * 128 + mh * 64 + mm * 16 + lr) * 64 + (((kk * 4 + lq) ^ sx) * 8));
  };
  auto read_b = [&](bfrag (&d)[4], int buf, int nh) {
    const bf16_t* base = Bbase(buf);
#pragma unroll
    for (int nn = 0; nn < 2; ++nn)
#pragma unroll
      for (int kk = 0; kk < 2; ++kk)
        d[nn * 2 + kk] = *reinterpret_cast<const bfrag*>(
            base + (wc * 64 + nh * 32 + nn * 16 + lr) * 64 + (((kk * 4 + lq) ^ sx) * 8));
  };

  auto tile = [&](int tt, int v1, int v2, int v3, int v4, bool s12, bool s34, bool r34) {
    const int cur = tt & 1, nxt = cur ^ 1;
    // ---- phase 1: MFMA(aP,bP); read bQ (this tile nh1); stage B(t+1,r1)
    read_b(bQ, cur, 1);
    if (s12) stage_B(tt + 1, nxt, 1);
    __builtin_amdgcn_sched_barrier(0);
    __builtin_amdgcn_s_setprio(1);
    QUAD(aP, bP, 0, 0);
    __builtin_amdgcn_s_setprio(0);
    __builtin_amdgcn_sched_barrier(0);
    vwait(v1);
    __builtin_amdgcn_s_barrier();
    // ---- phase 2: MFMA(aP,bQ); read aQ (this tile mh1); stage A(t+1,r1)
    read_a(aQ, cur, 1);
    if (s12) stage_A(tt + 1, nxt, 1);
    __builtin_amdgcn_sched_barrier(0);
    __builtin_amdgcn_s_setprio(1);
    QUAD(aP, bQ, 0, 2);
    __builtin_amdgcn_s_setprio(0);
    __builtin_amdgcn_sched_barrier(0);
    vwait(v2);
    __builtin_amdgcn_s_barrier();
    // ---- phase 3: MFMA(aQ,bP); read aP <- next tile mh0; stage A(t+2,r0)
    if (r34) read_a(aP, nxt, 0);
    if (s34) stage_A(tt + 2, cur, 0);
    __builtin_amdgcn_sched_barrier(0);
    __builtin_amdgcn_s_setprio(1);
    QUAD(aQ, bP, 4, 0);
    __builtin_amdgcn_s_setprio(0);
    __builtin_amdgcn_sched_barrier(0);
    vwait(v3);
    __builtin_amdgcn_s_barrier();
    // ---- phase 4: MFMA(aQ,bQ); read bP <- next tile nh0; stage B(t+2,r0)
    if (r34) read_b(bP, nxt, 0);
    if (s34) stage_B(tt + 2, cur, 0);
    __builtin_amdgcn_sched_barrier(0);
    __builtin_amdgcn_s_setprio(1);
    QUAD(aQ, bQ, 4, 2);
    __builtin_amdgcn_s_setprio(0);
    __builtin_amdgcn_sched_barrier(0);
    vwait(v4);
    __builtin_amdgcn_s_barrier();
  };

  // prologue: tile0 all regions + tile1 r0 pair (12 loads); then pre-read ph1 frags
  stage_A(0, 0, 0); stage_B(0, 0, 0);
  stage_A(0, 0, 1); stage_B(0, 0, 1);
  stage_A(1, 1, 0); stage_B(1, 1, 0);
  vwait(4);
  __builtin_amdgcn_s_barrier();
  read_a(aP, 0, 0);
  read_b(bP, 0, 0);

  for (int tt = 0; tt < 7; ++tt)
    tile(tt, 6, 6, 6, 6, true, true, true);   // st3/st4 stage t+2 (max kt=8)
  tile(7, 6, 6, 4, 2, true, false, true);
  tile(8, 0, 0, 0, 0, false, false, false);

  __syncthreads();

  // ---- epilogue: per-wave private gate fusion ----
  float* Gw = (float*)smem + w * 2176;
  const float* biasn = biasc + mat * kNG + bn * 256 + wc * 64;
  float bb[4];
#pragma unroll
  for (int n = 0; n < 4; ++n) bb[n] = biasn[n * 16 + lr];
  const int rowg0 = bm * 256 + wr * 128;
  const int unit = bn * 64 + wc * 16 + lr;
#pragma unroll
  for (int ch = 0; ch < 4; ++ch) {
#pragma unroll
    for (int mm = 0; mm < 2; ++mm) {
      const int m = ch * 2 + mm;
#pragma unroll
      for (int n = 0; n < 4; ++n)
#pragma unroll
        for (int j = 0; j < 4; ++j)
          Gw[(mm * 16 + lq * 4 + j) * 68 + n * 16 + lr] = acc[m][n][j] + bb[n];
    }
#pragma unroll
    for (int rr = 0; rr < 8; ++rr) {
      const int row = rr * 4 + lq;
      const float4 g4 = *reinterpret_cast<const float4*>(&Gw[row * 68 + lr * 4]);
      const float iv = sigf(g4.x);
      const float fv = sigf(g4.y);
      const float gv = tanh_fast(g4.z);
      const float ov = sigf(g4.w);
      const int grow = rowg0 + ch * 32 + row;
      const size_t cidx = ((size_t)cell * kB + grow) * kH + unit;
      const float cn = fv * cbuf[cidx] + iv * gv;
      cbuf[cidx] = cn;
      hout[cidx] = (bf16_t)(ov * tanh_fast(cn));
    }
  }
}

// ---------------- head ----------------

__global__ __launch_bounds__(256) void head_kernel(const bf16_t* __restrict__ hfin,
                                                   const float* __restrict__ W3,
                                                   const float* __restrict__ b3,
                                                   float* __restrict__ out) {
  const int b = blockIdx.x, t = threadIdx.x;
  float acc[10];
#pragma unroll
  for (int j = 0; j < 10; ++j) acc[j] = 0.f;
  for (int k = t; k < 2048; k += 256) {
    const int cell = k >> 9, u = k & 511;
    const float hv = (float)hfin[((size_t)cell * kB + b) * kH + u];
#pragma unroll
    for (int j = 0; j < 10; ++j) acc[j] += hv * W3[j * 2048 + k];
  }
  __shared__ float red[256];
  __shared__ float logits[10];
  for (int j = 0; j < 10; ++j) {
    red[t] = acc[j];
    __syncthreads();
    for (int o2 = 128; o2 > 0; o2 >>= 1) {
      if (t < o2) red[t] += red[t + o2];
      __syncthreads();
    }
    if (t == 0) logits[j] = red[0] + b3[j];
    __syncthreads();
  }
  if (t == 0) {
    float mx = logits[0];
    for (int j = 1; j < 10; ++j) mx = fmaxf(mx, logits[j]);
    float se = 0.f;
    for (int j = 0; j < 10; ++j) se += expf(logits[j] - mx);
    const float lse = mx + logf(se);
    for (int j = 0; j < 10; ++j) out[(size_t)b * 10 + j] = logits[j] - lse;
  }
}

}  // namespace

extern "C" void kernel_launch(void* const* d_in, const int* in_sizes, int n_in,
                              void* d_out, int out_size, void* d_ws, size_t ws_size,
                              hipStream_t stream) {
  const float* x     = (const float*)d_in[0];
  const float* h0    = (const float*)d_in[1];
  const float* c0    = (const float*)d_in[2];
  const float* W1    = (const float*)d_in[3];
  const float* b1    = (const float*)d_in[4];
  const float* Wih_l = (const float*)d_in[5];
  const float* Whh_l = (const float*)d_in[6];
  const float* bih_l = (const float*)d_in[7];
  const float* bhh_l = (const float*)d_in[8];
  const float* Wih_r = (const float*)d_in[9];
  const float* Whh_r = (const float*)d_in[10];
  const float* bih_r = (const float*)d_in[11];
  const float* bhh_r = (const float*)d_in[12];
  const float* Wih_d = (const float*)d_in[13];
  const float* Whh_d = (const float*)d_in[14];
  const float* bih_d = (const float*)d_in[15];
  const float* bhh_d = (const float*)d_in[16];
  const float* W3    = (const float*)d_in[17];
  const float* b3    = (const float*)d_in[18];
  float* out = (float*)d_out;

  char* p = (char*)d_ws;
  auto take = [&](size_t bytes) {
    char* r = p;
    p += (bytes + 255) & ~(size_t)255;
    return r;
  };
  bf16_t* xb    = (bf16_t*)take((size_t)kB * kIN * 2);   // later reused as featT
  bf16_t* w1b   = (bf16_t*)take((size_t)kFS * kIN * 2);  // later reused as hbuf (2 slots)
  bf16_t* feat  = (bf16_t*)take((size_t)kB * kFS * 2);
  bf16_t* wcat  = (bf16_t*)take((size_t)3 * kNG * kKC * 2);
  float*  biasc = (float*)take((size_t)3 * kNG * 4);
  float*  cbuf  = (float*)take((size_t)4 * kB * kH * 4);
  bf16_t* featT = xb;   // safe: gemm_feat (reads xb) precedes transpose (writes featT)
  bf16_t* hbuf  = w1b;  // safe: gemm_feat (reads w1b) precedes pack_hc
  const size_t HSZ = (size_t)4 * kB * kH;

  (void)hipFuncSetAttribute(reinterpret_cast<const void*>(&lstm_step256_kernel),
                            hipFuncAttributeMaxDynamicSharedMemorySize, 131072);

  f2b4_kernel<<<(kB * kIN / 4) / 256, 256, 0, stream>>>(x, xb, kB * kIN / 4);
  f2b4_kernel<<<(kFS * kIN / 4) / 256, 256, 0, stream>>>(W1, w1b, kFS * kIN / 4);
  gemm_feat_kernel<<<dim3(1024), 256, 0, stream>>>(xb, w1b, b1, feat);
  transpose64_kernel<<<kB, 256, 0, stream>>>(feat, featT);
  pack_wcat_kernel<<<(3 * kNG * kKC + 255) / 256, 256, 0, stream>>>(
      Wih_l, Whh_l, Wih_r, Whh_r, Wih_d, Whh_d, wcat);
  pack_bias_kernel<<<(3 * kNG + 255) / 256, 256, 0, stream>>>(
      bih_l, bhh_l, bih_r, bhh_r, bih_d, bhh_d, biasc);
  pack_hc_kernel<<<(int)(HSZ / 256), 256, 0, stream>>>(h0, c0, hbuf, cbuf, (int)HSZ);

  for (int s = 0; s < 64; ++s) {
    lstm_step256_kernel<<<dim3(512), 512, 131072, stream>>>(
        feat, featT, wcat, biasc,
        hbuf + (size_t)(s & 1) * HSZ, hbuf + (size_t)((s + 1) & 1) * HSZ, cbuf, s);
  }
  head_kernel<<<kB, 256, 0, stream>>>(hbuf, W3, b3, out);
}

// Round 8
// 4117.840 us; speedup vs baseline: 1.1008x; 1.1008x over previous
//
#include <hip/hip_runtime.h>
#include <cstddef>
#include <cstdint>

namespace {

constexpr int kB  = 4096;   // batch
constexpr int kIN = 4096;
constexpr int kFS = 4096;
constexpr int kS  = 64;
constexpr int kH  = 512;
constexpr int kNG = 2048;   // 4*H
constexpr int kKC = 576;    // 64 (input slice) + 512 (hidden)

typedef __bf16 bf16_t;
typedef __bf16 bfrag  __attribute__((ext_vector_type(8)));
typedef __bf16 bf16v4 __attribute__((ext_vector_type(4)));
typedef float  f32x4  __attribute__((ext_vector_type(4)));

__device__ __forceinline__ void gload16(const void* g, void* l) {
  __builtin_amdgcn_global_load_lds(
      (const __attribute__((address_space(1))) void*)g,
      (__attribute__((address_space(3))) void*)l, 16, 0, 0);
}

__device__ __forceinline__ float sigf(float x) { return 1.0f / (1.0f + __expf(-x)); }
__device__ __forceinline__ float tanh_fast(float x) {
  float e = __expf(2.0f * x);
  return 1.0f - 2.0f / (e + 1.0f);
}

__device__ __forceinline__ f32x4 mfma16(bfrag a, bfrag b, f32x4 c) {
  return __builtin_amdgcn_mfma_f32_16x16x32_bf16(a, b, c, 0, 0, 0);
}

// ---------------- pack kernels (unchanged) ----------------

__global__ __launch_bounds__(256) void f2b4_kernel(const float* __restrict__ in,
                                                   bf16_t* __restrict__ out, int n4) {
  int i = blockIdx.x * 256 + threadIdx.x;
  if (i >= n4) return;
  float4 v = reinterpret_cast<const float4*>(in)[i];
  bf16v4 o = {(bf16_t)v.x, (bf16_t)v.y, (bf16_t)v.z, (bf16_t)v.w};
  *reinterpret_cast<bf16v4*>(out + (size_t)i * 4) = o;
}

__global__ __launch_bounds__(256) void pack_wcat_kernel(
    const float* __restrict__ Wih_l, const float* __restrict__ Whh_l,
    const float* __restrict__ Wih_r, const float* __restrict__ Whh_r,
    const float* __restrict__ Wih_d, const float* __restrict__ Whh_d,
    bf16_t* __restrict__ wcat) {
  int idx = blockIdx.x * 256 + threadIdx.x;
  if (idx >= 3 * kNG * kKC) return;
  int m = idx / (kNG * kKC);
  int rem = idx - m * (kNG * kKC);
  int rr = rem / kKC;
  int k  = rem - rr * kKC;
  int u = rr >> 2, g = rr & 3;
  int orow = g * kH + u;
  const float* Wih = (m == 0) ? Wih_l : (m == 1) ? Wih_r : Wih_d;
  const float* Whh = (m == 0) ? Whh_l : (m == 1) ? Whh_r : Whh_d;
  float v = (k < 64) ? Wih[(size_t)orow * 64 + k] : Whh[(size_t)orow * 512 + (k - 64)];
  wcat[idx] = (bf16_t)v;
}

__global__ __launch_bounds__(256) void pack_bias_kernel(
    const float* __restrict__ bih_l, const float* __restrict__ bhh_l,
    const float* __restrict__ bih_r, const float* __restrict__ bhh_r,
    const float* __restrict__ bih_d, const float* __restrict__ bhh_d,
    float* __restrict__ biasc) {
  int idx = blockIdx.x * 256 + threadIdx.x;
  if (idx >= 3 * kNG) return;
  int m = idx / kNG;
  int rr = idx - m * kNG;
  int u = rr >> 2, g = rr & 3;
  int orow = g * kH + u;
  const float* bi = (m == 0) ? bih_l : (m == 1) ? bih_r : bih_d;
  const float* bh = (m == 0) ? bhh_l : (m == 1) ? bhh_r : bhh_d;
  biasc[idx] = bi[orow] + bh[orow];
}

__global__ __launch_bounds__(256) void pack_hc_kernel(const float* __restrict__ h0,
                                                      const float* __restrict__ c0,
                                                      bf16_t* __restrict__ hbuf0,
                                                      float* __restrict__ cbuf, int n) {
  int i = blockIdx.x * 256 + threadIdx.x;
  if (i >= n) return;
  hbuf0[i] = (bf16_t)h0[i];
  cbuf[i]  = c0[i];
}

__global__ __launch_bounds__(256) void transpose64_kernel(const bf16_t* __restrict__ feat,
                                                          bf16_t* __restrict__ featT) {
  __shared__ bf16_t tile[64][65];
  const int b = blockIdx.x;
  const bf16_t* src = feat + (size_t)b * kFS;
  bf16_t* dst = featT + (size_t)b * kFS;
  for (int i = threadIdx.x; i < 4096; i += 256) tile[i >> 6][i & 63] = src[i];
  __syncthreads();
  for (int i = threadIdx.x; i < 4096; i += 256) dst[i] = tile[i & 63][i >> 6];
}

// ---------------- feat GEMM (R4 version, unchanged) ----------------

__global__ __launch_bounds__(256, 4) void gemm_feat_kernel(
    const bf16_t* __restrict__ X, const bf16_t* __restrict__ W,
    const float* __restrict__ b1, bf16_t* __restrict__ feat) {
  __shared__ bf16_t As[128 * 32];
  __shared__ bf16_t Bs[128 * 32];
  const int t = threadIdx.x;
  const int bid = blockIdx.x;
  const int widx = (bid & 7) * 128 + (bid >> 3);
  const int bm = widx & 31, bn = widx >> 5;
  const int w = t >> 6, l = t & 63;
  const int wm = (w >> 1) * 64, wn = (w & 1) * 64;
  const int sr = t >> 2;
  const int skS = ((t & 3) ^ ((t >> 3) & 3)) * 8;
  const int lr = l & 15;
  const int lkS = ((l >> 4) ^ ((l >> 1) & 3)) * 8;
  const int lrow4 = (l >> 4) * 4;

  f32x4 acc[4][4];
#pragma unroll
  for (int i = 0; i < 4; ++i)
#pragma unroll
    for (int j = 0; j < 4; ++j) acc[i][j] = (f32x4){0.f, 0.f, 0.f, 0.f};

  const bf16_t* ga = X + (size_t)(bm * 128 + sr) * kIN + skS;
  const bf16_t* gb = W + (size_t)(bn * 128 + sr) * kIN + skS;
  bf16_t* lA = As + w * 512;
  bf16_t* lB = Bs + w * 512;

  for (int kt = 0; kt < kIN / 32; ++kt) {
    gload16(ga, lA);
    gload16(ga + (size_t)64 * kIN, lA + 2048);
    gload16(gb, lB);
    gload16(gb + (size_t)64 * kIN, lB + 2048);
    ga += 32; gb += 32;
    __syncthreads();
    bfrag a[4], b[4];
#pragma unroll
    for (int mi = 0; mi < 4; ++mi)
      a[mi] = *reinterpret_cast<const bfrag*>(&As[(wm + mi * 16 + lr) * 32 + lkS]);
#pragma unroll
    for (int ni = 0; ni < 4; ++ni)
      b[ni] = *reinterpret_cast<const bfrag*>(&Bs[(wn + ni * 16 + lr) * 32 + lkS]);
#pragma unroll
    for (int mi = 0; mi < 4; ++mi)
#pragma unroll
      for (int ni = 0; ni < 4; ++ni)
        acc[mi][ni] = __builtin_amdgcn_mfma_f32_16x16x32_bf16(a[mi], b[ni], acc[mi][ni], 0, 0, 0);
    __syncthreads();
  }

#pragma unroll
  for (int ni = 0; ni < 4; ++ni) {
    const int col = bn * 128 + wn + ni * 16 + lr;
    const float bb = b1[col];
#pragma unroll
    for (int mi = 0; mi < 4; ++mi) {
#pragma unroll
      for (int r = 0; r < 4; ++r) {
        const int row = bm * 128 + wm + mi * 16 + lrow4 + r;
        float v = acc[mi][ni][r] + bb;
        feat[(size_t)row * kFS + col] = (bf16_t)fmaxf(v, 0.0f);
      }
    }
  }
}

// ---------------- 128x128 BK=64 double-buffered step kernel, 2 blocks/CU ----------------
// LDS (dynamic 64 KB): buf b at smem + b*32768: A[128][64] bf16 (16KB) + B[128][64] (16KB).
// Per K-tile: issue 8 global_load_lds for tile t+1 into buf^1 FIRST, then 16 ds_read_b128
// + 32 MFMA on buf; vmcnt(0) at tile end is ~free (loads had the whole MFMA burst to land).
// One raw s_barrier per tile. T2 swizzle (slot ^= row&7) via pre-swizzled global source.
// 64 KB LDS + ~170 VGPR -> 2 blocks/CU: block X's epilogue/prologue overlaps block Y's MFMA.
// Epilogue is per-wave private (Gw in the dead buf1 region; last tile reads buf0) - no barriers.

__global__ __launch_bounds__(256, 2) void lstm_step128_kernel(
    const bf16_t* __restrict__ feat, const bf16_t* __restrict__ featT,
    const bf16_t* __restrict__ wcat, const float* __restrict__ biasc,
    const bf16_t* __restrict__ hin, bf16_t* __restrict__ hout,
    float* __restrict__ cbuf, int s) {
  extern __shared__ __align__(16) char smem[];

  const int t = threadIdx.x;
  const int l = t & 63, w = t >> 6;
  const int wm = (w >> 1) * 64, wn = (w & 1) * 64;
  const int lr = l & 15, lq = l >> 4;
  const int sx = lr & 7;
  const int srow = l >> 3;              // row within 8-row group (= row & 7)
  const int sslot = (l & 7) ^ srow;     // pre-swizzled global 16B-slot

  // grid 2048 = 4 cell x 32 bm x 16 bn; XCD swizzle (bijective, 2048 % 8 == 0)
  const int bid = blockIdx.x;
  const int widx = (bid & 7) * 256 + (bid >> 3);
  const int cell = widx >> 9;
  const int rwk = widx & 511;
  const int bm = rwk >> 4, bn = rwk & 15;

  const bf16_t* xsrc = (cell < 2) ? feat : featT;
  const int off = ((cell & 1) ? (63 - s) : s) * 64;
  const int mat = (cell < 2) ? cell : 2;
  const bf16_t* Wm = wcat + (size_t)mat * kNG * kKC;
  const bf16_t* hc = hin + (size_t)cell * kB * kH;

  auto stage = [&](int kt, int buf) {
    char* base = smem + buf * 32768;
#pragma unroll
    for (int j = 0; j < 4; ++j) {                     // A: 128 rows x 64 K
      const int row0 = j * 32 + w * 8;                // wave-uniform
      bf16_t* dst = (bf16_t*)base + row0 * 64;
      const bf16_t* src = (kt == 0)
          ? xsrc + (size_t)(bm * 128 + row0 + srow) * kFS + off + sslot * 8
          : hc + (size_t)(bm * 128 + row0 + srow) * kH + (kt - 1) * 64 + sslot * 8;
      gload16(src, dst);
    }
#pragma unroll
    for (int j = 0; j < 4; ++j) {                     // B: 128 rows x 64 K
      const int row0 = j * 32 + w * 8;
      bf16_t* dst = (bf16_t*)(base + 16384) + row0 * 64;
      const bf16_t* src =
          Wm + (size_t)(bn * 128 + row0 + srow) * kKC + kt * 64 + sslot * 8;
      gload16(src, dst);
    }
  };

  f32x4 acc[4][4];
#pragma unroll
  for (int i = 0; i < 4; ++i)
#pragma unroll
    for (int j = 0; j < 4; ++j) acc[i][j] = (f32x4){0.f, 0.f, 0.f, 0.f};

  // prologue
  stage(0, 0);
  asm volatile("s_waitcnt vmcnt(0)" ::: "memory");
  __builtin_amdgcn_sched_barrier(0);
  __builtin_amdgcn_s_barrier();

  for (int kt = 0; kt < 9; ++kt) {
    const int cur = kt & 1;
    if (kt < 8) stage(kt + 1, cur ^ 1);   // issue early; lands under this tile's MFMA
    const bf16_t* As_ = (const bf16_t*)(smem + cur * 32768);
    const bf16_t* Bs_ = (const bf16_t*)(smem + cur * 32768 + 16384);
    bfrag a[8], b[8];
#pragma unroll
    for (int mi = 0; mi < 4; ++mi)
#pragma unroll
      for (int kk = 0; kk < 2; ++kk)
        a[mi * 2 + kk] = *reinterpret_cast<const bfrag*>(
            As_ + (wm + mi * 16 + lr) * 64 + (((kk * 4 + lq) ^ sx) * 8));
#pragma unroll
    for (int ni = 0; ni < 4; ++ni)
#pragma unroll
      for (int kk = 0; kk < 2; ++kk)
        b[ni * 2 + kk] = *reinterpret_cast<const bfrag*>(
            Bs_ + (wn + ni * 16 + lr) * 64 + (((kk * 4 + lq) ^ sx) * 8));
    __builtin_amdgcn_s_setprio(1);
#pragma unroll
    for (int kk = 0; kk < 2; ++kk)
#pragma unroll
      for (int mi = 0; mi < 4; ++mi)
#pragma unroll
        for (int ni = 0; ni < 4; ++ni)
          acc[mi][ni] = mfma16(a[mi * 2 + kk], b[ni * 2 + kk], acc[mi][ni]);
    __builtin_amdgcn_s_setprio(0);
    __builtin_amdgcn_sched_barrier(0);
    asm volatile("s_waitcnt vmcnt(0)" ::: "memory");   // next tile landed (cheap: post-MFMA)
    __builtin_amdgcn_sched_barrier(0);
    __builtin_amdgcn_s_barrier();
  }

  // ---- epilogue: per-wave private gate fusion; Gw in dead buf1 region ----
  // Wave tile 64x64 = 16 complete units x 64 rows. 4 chunks of 16 rows.
  float* Gw = (float*)(smem + 32768 + w * 4352);   // 16 x 68 f32 per wave
  const float* biasn = biasc + mat * kNG + bn * 128 + wn;
  float bb[4];
#pragma unroll
  for (int n = 0; n < 4; ++n) bb[n] = biasn[n * 16 + lr];
  const int rowg0 = bm * 128 + wm;
  const int unit0 = bn * 32 + (w & 1) * 16;
#pragma unroll
  for (int mi = 0; mi < 4; ++mi) {
#pragma unroll
    for (int n = 0; n < 4; ++n)
#pragma unroll
      for (int j = 0; j < 4; ++j)
        Gw[(lq * 4 + j) * 68 + n * 16 + lr] = acc[mi][n][j] + bb[n];
#pragma unroll
    for (int it = 0; it < 4; ++it) {
      const int item = it * 64 + l;        // 16 rows x 16 units
      const int row = item >> 4;
      const int u = item & 15;
      const float4 g4 = *reinterpret_cast<const float4*>(&Gw[row * 68 + u * 4]);
      const float iv = sigf(g4.x);
      const float fv = sigf(g4.y);
      const float gv = tanh_fast(g4.z);
      const float ov = sigf(g4.w);
      const int grow = rowg0 + mi * 16 + row;
      const size_t cidx = ((size_t)cell * kB + grow) * kH + unit0 + u;
      const float cn = fv * cbuf[cidx] + iv * gv;
      cbuf[cidx] = cn;
      hout[cidx] = (bf16_t)(ov * tanh_fast(cn));
    }
    // same-wave LDS write->read dependency handled by compiler lgkmcnt; no barrier needed
  }
}

// ---------------- head: wave shuffle reduce (no LDS trees) ----------------

__global__ __launch_bounds__(256) void head_kernel(const bf16_t* __restrict__ hfin,
                                                   const float* __restrict__ W3,
                                                   const float* __restrict__ b3,
                                                   float* __restrict__ out) {
  const int b = blockIdx.x, t = threadIdx.x;
  const int l = t & 63, w = t >> 6;
  float acc[10];
#pragma unroll
  for (int j = 0; j < 10; ++j) acc[j] = 0.f;
  for (int k = t; k < 2048; k += 256) {
    const int cell = k >> 9, u = k & 511;
    const float hv = (float)hfin[((size_t)cell * kB + b) * kH + u];
#pragma unroll
    for (int j = 0; j < 10; ++j) acc[j] += hv * W3[j * 2048 + k];
  }
#pragma unroll
  for (int j = 0; j < 10; ++j)
#pragma unroll
    for (int o = 32; o > 0; o >>= 1) acc[j] += __shfl_down(acc[j], o, 64);
  __shared__ float wred[4][10];
  if (l == 0)
#pragma unroll
    for (int j = 0; j < 10; ++j) wred[w][j] = acc[j];
  __syncthreads();
  if (t == 0) {
    float logits[10];
#pragma unroll
    for (int j = 0; j < 10; ++j)
      logits[j] = wred[0][j] + wred[1][j] + wred[2][j] + wred[3][j] + b3[j];
    float mx = logits[0];
#pragma unroll
    for (int j = 1; j < 10; ++j) mx = fmaxf(mx, logits[j]);
    float se = 0.f;
#pragma unroll
    for (int j = 0; j < 10; ++j) se += expf(logits[j] - mx);
    const float lse = mx + logf(se);
#pragma unroll
    for (int j = 0; j < 10; ++j) out[(size_t)b * 10 + j] = logits[j] - lse;
  }
}

}  // namespace

extern "C" void kernel_launch(void* const* d_in, const int* in_sizes, int n_in,
                              void* d_out, int out_size, void* d_ws, size_t ws_size,
                              hipStream_t stream) {
  const float* x     = (const float*)d_in[0];
  const float* h0    = (const float*)d_in[1];
  const float* c0    = (const float*)d_in[2];
  const float* W1    = (const float*)d_in[3];
  const float* b1    = (const float*)d_in[4];
  const float* Wih_l = (const float*)d_in[5];
  const float* Whh_l = (const float*)d_in[6];
  const float* bih_l = (const float*)d_in[7];
  const float* bhh_l = (const float*)d_in[8];
  const float* Wih_r = (const float*)d_in[9];
  const float* Whh_r = (const float*)d_in[10];
  const float* bih_r = (const float*)d_in[11];
  const float* bhh_r = (const float*)d_in[12];
  const float* Wih_d = (const float*)d_in[13];
  const float* Whh_d = (const float*)d_in[14];
  const float* bih_d = (const float*)d_in[15];
  const float* bhh_d = (const float*)d_in[16];
  const float* W3    = (const float*)d_in[17];
  const float* b3    = (const float*)d_in[18];
  float* out = (float*)d_out;

  char* p = (char*)d_ws;
  auto take = [&](size_t bytes) {
    char* r = p;
    p += (bytes + 255) & ~(size_t)255;
    return r;
  };
  bf16_t* xb    = (bf16_t*)take((size_t)kB * kIN * 2);   // later reused as featT
  bf16_t* w1b   = (bf16_t*)take((size_t)kFS * kIN * 2);  // later reused as hbuf (2 slots)
  bf16_t* feat  = (bf16_t*)take((size_t)kB * kFS * 2);
  bf16_t* wcat  = (bf16_t*)take((size_t)3 * kNG * kKC * 2);
  float*  biasc = (float*)take((size_t)3 * kNG * 4);
  float*  cbuf  = (float*)take((size_t)4 * kB * kH * 4);
  bf16_t* featT = xb;   // safe: gemm_feat (reads xb) precedes transpose (writes featT)
  bf16_t* hbuf  = w1b;  // safe: gemm_feat (reads w1b) precedes pack_hc
  const size_t HSZ = (size_t)4 * kB * kH;

  (void)hipFuncSetAttribute(reinterpret_cast<const void*>(&lstm_step128_kernel),
                            hipFuncAttributeMaxDynamicSharedMemorySize, 65536);

  f2b4_kernel<<<(kB * kIN / 4) / 256, 256, 0, stream>>>(x, xb, kB * kIN / 4);
  f2b4_kernel<<<(kFS * kIN / 4) / 256, 256, 0, stream>>>(W1, w1b, kFS * kIN / 4);
  gemm_feat_kernel<<<dim3(1024), 256, 0, stream>>>(xb, w1b, b1, feat);
  transpose64_kernel<<<kB, 256, 0, stream>>>(feat, featT);
  pack_wcat_kernel<<<(3 * kNG * kKC + 255) / 256, 256, 0, stream>>>(
      Wih_l, Whh_l, Wih_r, Whh_r, Wih_d, Whh_d, wcat);
  pack_bias_kernel<<<(3 * kNG + 255) / 256, 256, 0, stream>>>(
      bih_l, bhh_l, bih_r, bhh_r, bih_d, bhh_d, biasc);
  pack_hc_kernel<<<(int)(HSZ / 256), 256, 0, stream>>>(h0, c0, hbuf, cbuf, (int)HSZ);

  for (int s = 0; s < 64; ++s) {
    lstm_step128_kernel<<<dim3(2048), 256, 65536, stream>>>(
        feat, featT, wcat, biasc,
        hbuf + (size_t)(s & 1) * HSZ, hbuf + (size_t)((s + 1) & 1) * HSZ, cbuf, s);
  }
  head_kernel<<<kB, 256, 0, stream>>>(hbuf, W3, b3, out);
}

// Round 9
// 3841.521 us; speedup vs baseline: 1.1799x; 1.0719x over previous
//
#include <hip/hip_runtime.h>
#include <cstddef>
#include <cstdint>

namespace {

constexpr int kB  = 4096;   // batch
constexpr int kIN = 4096;
constexpr int kFS = 4096;
constexpr int kS  = 64;
constexpr int kH  = 512;
constexpr int kNG = 2048;   // 4*H
constexpr int kKC = 576;    // 64 (input slice) + 512 (hidden)

typedef __bf16 bf16_t;
typedef __bf16 bfrag  __attribute__((ext_vector_type(8)));
typedef __bf16 bf16v4 __attribute__((ext_vector_type(4)));
typedef float  f32x4  __attribute__((ext_vector_type(4)));

__device__ __forceinline__ void gload16(const void* g, void* l) {
  __builtin_amdgcn_global_load_lds(
      (const __attribute__((address_space(1))) void*)g,
      (__attribute__((address_space(3))) void*)l, 16, 0, 0);
}

__device__ __forceinline__ float sigf(float x) { return 1.0f / (1.0f + __expf(-x)); }
__device__ __forceinline__ float tanh_fast(float x) {
  float e = __expf(2.0f * x);
  return 1.0f - 2.0f / (e + 1.0f);
}

__device__ __forceinline__ f32x4 mfma16(bfrag a, bfrag b, f32x4 c) {
  return __builtin_amdgcn_mfma_f32_16x16x32_bf16(a, b, c, 0, 0, 0);
}

// ---------------- pack kernels ----------------

__global__ __launch_bounds__(256) void f2b4_kernel(const float* __restrict__ in,
                                                   bf16_t* __restrict__ out, int n4) {
  int i = blockIdx.x * 256 + threadIdx.x;
  if (i >= n4) return;
  float4 v = reinterpret_cast<const float4*>(in)[i];
  bf16v4 o = {(bf16_t)v.x, (bf16_t)v.y, (bf16_t)v.z, (bf16_t)v.w};
  *reinterpret_cast<bf16v4*>(out + (size_t)i * 4) = o;
}

// wcat2: MFMA-fragment-order weight pack.
// chunk (mat, nb, kt, kk) = 64 lanes x 8 bf16 (1 KB); lane l holds W[col][k0..k0+7]
// with col = nb*16 + (l&15), k = kt*64 + kk*32 + (l>>4)*8.
// Gate mapping baked in: col c -> gate=(c>>4)&3, unit=(c>>6)*16 + (c&15);
// original weight row = gate*512 + unit. k<64 -> Wih (x-slice), else Whh[k-64].
__global__ __launch_bounds__(256) void pack_wcat2_kernel(
    const float* __restrict__ Wih_l, const float* __restrict__ Whh_l,
    const float* __restrict__ Wih_r, const float* __restrict__ Whh_r,
    const float* __restrict__ Wih_d, const float* __restrict__ Whh_d,
    bf16_t* __restrict__ wcat2) {
  const int total = 3 * 128 * 9 * 2 * 64 * 8;
  int idx = blockIdx.x * 256 + threadIdx.x;
  if (idx >= total) return;
  int e  = idx & 7;
  int l  = (idx >> 3) & 63;
  int kk = (idx >> 9) & 1;
  int r  = idx >> 10;            // (mat*128+nb)*9 + kt
  int kt = r % 9;
  int matnb = r / 9;
  int mat = matnb >> 7;
  int nb  = matnb & 127;
  const int c = nb * 16 + (l & 15);
  const int g = (c >> 4) & 3;
  const int u = (c >> 6) * 16 + (c & 15);
  const int orow = g * kH + u;
  const int k = kt * 64 + kk * 32 + (l >> 4) * 8 + e;
  const float* Wih = (mat == 0) ? Wih_l : (mat == 1) ? Wih_r : Wih_d;
  const float* Whh = (mat == 0) ? Whh_l : (mat == 1) ? Whh_r : Whh_d;
  float v = (k < 64) ? Wih[(size_t)orow * 64 + k] : Whh[(size_t)orow * 512 + (k - 64)];
  wcat2[idx] = (bf16_t)v;
}

__global__ __launch_bounds__(256) void pack_bias_kernel(
    const float* __restrict__ bih_l, const float* __restrict__ bhh_l,
    const float* __restrict__ bih_r, const float* __restrict__ bhh_r,
    const float* __restrict__ bih_d, const float* __restrict__ bhh_d,
    float* __restrict__ biasc) {
  int idx = blockIdx.x * 256 + threadIdx.x;
  if (idx >= 3 * kNG) return;
  int mat = idx / kNG;
  int c = idx - mat * kNG;
  int g = (c >> 4) & 3;
  int u = (c >> 6) * 16 + (c & 15);
  int orow = g * kH + u;
  const float* bi = (mat == 0) ? bih_l : (mat == 1) ? bih_r : bih_d;
  const float* bh = (mat == 0) ? bhh_l : (mat == 1) ? bhh_r : bhh_d;
  biasc[idx] = bi[orow] + bh[orow];
}

__global__ __launch_bounds__(256) void pack_hc_kernel(const float* __restrict__ h0,
                                                      const float* __restrict__ c0,
                                                      bf16_t* __restrict__ hbuf0,
                                                      float* __restrict__ cbuf, int n) {
  int i = blockIdx.x * 256 + threadIdx.x;
  if (i >= n) return;
  hbuf0[i] = (bf16_t)h0[i];
  cbuf[i]  = c0[i];
}

__global__ __launch_bounds__(256) void transpose64_kernel(const bf16_t* __restrict__ feat,
                                                          bf16_t* __restrict__ featT) {
  __shared__ bf16_t tile[64][65];
  const int b = blockIdx.x;
  const bf16_t* src = feat + (size_t)b * kFS;
  bf16_t* dst = featT + (size_t)b * kFS;
  for (int i = threadIdx.x; i < 4096; i += 256) tile[i >> 6][i & 63] = src[i];
  __syncthreads();
  for (int i = threadIdx.x; i < 4096; i += 256) dst[i] = tile[i & 63][i >> 6];
}

// ---------------- feat GEMM (unchanged) ----------------

__global__ __launch_bounds__(256, 4) void gemm_feat_kernel(
    const bf16_t* __restrict__ X, const bf16_t* __restrict__ W,
    const float* __restrict__ b1, bf16_t* __restrict__ feat) {
  __shared__ bf16_t As[128 * 32];
  __shared__ bf16_t Bs[128 * 32];
  const int t = threadIdx.x;
  const int bid = blockIdx.x;
  const int widx = (bid & 7) * 128 + (bid >> 3);
  const int bm = widx & 31, bn = widx >> 5;
  const int w = t >> 6, l = t & 63;
  const int wm = (w >> 1) * 64, wn = (w & 1) * 64;
  const int sr = t >> 2;
  const int skS = ((t & 3) ^ ((t >> 3) & 3)) * 8;
  const int lr = l & 15;
  const int lkS = ((l >> 4) ^ ((l >> 1) & 3)) * 8;
  const int lrow4 = (l >> 4) * 4;

  f32x4 acc[4][4];
#pragma unroll
  for (int i = 0; i < 4; ++i)
#pragma unroll
    for (int j = 0; j < 4; ++j) acc[i][j] = (f32x4){0.f, 0.f, 0.f, 0.f};

  const bf16_t* ga = X + (size_t)(bm * 128 + sr) * kIN + skS;
  const bf16_t* gb = W + (size_t)(bn * 128 + sr) * kIN + skS;
  bf16_t* lA = As + w * 512;
  bf16_t* lB = Bs + w * 512;

  for (int kt = 0; kt < kIN / 32; ++kt) {
    gload16(ga, lA);
    gload16(ga + (size_t)64 * kIN, lA + 2048);
    gload16(gb, lB);
    gload16(gb + (size_t)64 * kIN, lB + 2048);
    ga += 32; gb += 32;
    __syncthreads();
    bfrag a[4], b[4];
#pragma unroll
    for (int mi = 0; mi < 4; ++mi)
      a[mi] = *reinterpret_cast<const bfrag*>(&As[(wm + mi * 16 + lr) * 32 + lkS]);
#pragma unroll
    for (int ni = 0; ni < 4; ++ni)
      b[ni] = *reinterpret_cast<const bfrag*>(&Bs[(wn + ni * 16 + lr) * 32 + lkS]);
#pragma unroll
    for (int mi = 0; mi < 4; ++mi)
#pragma unroll
      for (int ni = 0; ni < 4; ++ni)
        acc[mi][ni] = __builtin_amdgcn_mfma_f32_16x16x32_bf16(a[mi], b[ni], acc[mi][ni], 0, 0, 0);
    __syncthreads();
  }

#pragma unroll
  for (int ni = 0; ni < 4; ++ni) {
    const int col = bn * 128 + wn + ni * 16 + lr;
    const float bb = b1[col];
#pragma unroll
    for (int mi = 0; mi < 4; ++mi) {
#pragma unroll
      for (int r = 0; r < 4; ++r) {
        const int row = bm * 128 + wm + mi * 16 + lrow4 + r;
        float v = acc[mi][ni][r] + bb;
        feat[(size_t)row * kFS + col] = (bf16_t)fmaxf(v, 0.0f);
      }
    }
  }
}

// ---------------- step kernel: 256x256, 8 waves (2Mx4N), B direct-from-global ----------------
// A via LDS (32 KB/tile, double-buffered, T2 swizzle). B fragments loaded straight from
// the fragment-ordered wcat2 with fully-coalesced dwordx4 (ping-pong register buffers,
// compile-time indexed via full unroll). One s_barrier per K-tile (protects A dbuf).
// Manual vmcnt(8) covers only the untracked global_load_lds stage; compiler auto-waits
// cover the b-loads. Epilogue: per-lane (no LDS, no shuffles) - lane's 4 nn-frags are
// the 4 gates of ONE unit by construction of wcat2's column mapping.

__global__ __launch_bounds__(512, 1) void lstm_step_kernel(
    const bf16_t* __restrict__ feat, const bf16_t* __restrict__ featT,
    const bf16_t* __restrict__ wcat2, const float* __restrict__ biasc,
    const bf16_t* __restrict__ hin, bf16_t* __restrict__ hout,
    float* __restrict__ cbuf, int s) {
  extern __shared__ __align__(16) char smem[];   // 2 x 32 KB A buffers

  const int t = threadIdx.x;
  const int l = t & 63, w = t >> 6;
  const int wr = w >> 2, wc = w & 3;   // 2M x 4N; wave tile 128 x 64
  const int lr = l & 15, lq = l >> 4;
  const int sx = lr & 7;
  const int srow = l >> 3;
  const int sslot = (l & 7) ^ (srow & 7);

  // grid 512 = 4 cell x 16 bm x 8 bn; XCD swizzle (bijective, 512 % 8 == 0)
  const int bid = blockIdx.x;
  const int widx = (bid & 7) * 64 + (bid >> 3);
  const int cell = widx >> 7;
  const int rwk = widx & 127;
  const int bm = rwk >> 3, bn = rwk & 7;

  const bf16_t* xsrc = (cell < 2) ? feat : featT;
  const int off = ((cell & 1) ? (63 - s) : s) * 64;
  const int mat = (cell < 2) ? cell : 2;
  const bf16_t* hc = hin + (size_t)cell * kB * kH;

  // A staging: 256 rows x 64 K per tile; 512 threads x 4 loads.
  auto stageA = [&](int kt, int buf) {
    bf16_t* base = (bf16_t*)(smem + buf * 32768);
#pragma unroll
    for (int j = 0; j < 4; ++j) {
      const int row0 = j * 64 + w * 8;          // wave-uniform
      bf16_t* dst = base + row0 * 64;
      const bf16_t* src = (kt == 0)
          ? xsrc + (size_t)(bm * 256 + row0 + srow) * kFS + off + sslot * 8
          : hc + (size_t)(bm * 256 + row0 + srow) * kH + (kt - 1) * 64 + sslot * 8;
      gload16(src, dst);
    }
  };

  // B fragment loads: chunk (mat, nb, kt, kk) at elem offset chunkIdx*512 + l*8.
  const size_t wb0 = ((size_t)mat * 128 + bn * 16 + wc * 4) * 9;   // chunk row for nn=0
  auto loadB = [&](int kt, bfrag (&d)[8]) {
#pragma unroll
    for (int nn = 0; nn < 4; ++nn)
#pragma unroll
      for (int kk = 0; kk < 2; ++kk)
        d[nn * 2 + kk] = *reinterpret_cast<const bfrag*>(
            wcat2 + (((wb0 + (size_t)nn * 9 + kt) * 2 + kk) << 9) + l * 8);
  };

  f32x4 acc[8][4];
#pragma unroll
  for (int i = 0; i < 8; ++i)
#pragma unroll
    for (int j = 0; j < 4; ++j) acc[i][j] = (f32x4){0.f, 0.f, 0.f, 0.f};

  bfrag bA[8], bB[8];

  // prologue
  stageA(0, 0);
  loadB(0, bA);
  asm volatile("s_waitcnt vmcnt(0)" ::: "memory");
  __builtin_amdgcn_sched_barrier(0);
  __builtin_amdgcn_s_barrier();

#pragma unroll
  for (int kt = 0; kt < 9; ++kt) {
    const int cur = kt & 1;
    const bf16_t* As_ = (const bf16_t*)(smem + cur * 32768);
    bfrag (&bCur)[8] = (kt & 1) ? bB : bA;
    bfrag (&bNxt)[8] = (kt & 1) ? bA : bB;

    if (kt < 8) stageA(kt + 1, cur ^ 1);

    bfrag a[8];
    // ---- sub-burst 1: mi 0..3 ----
#pragma unroll
    for (int mi = 0; mi < 4; ++mi)
#pragma unroll
      for (int kk = 0; kk < 2; ++kk)
        a[mi * 2 + kk] = *reinterpret_cast<const bfrag*>(
            As_ + (wr * 128 + mi * 16 + lr) * 64 + (((kk * 4 + lq) ^ sx) * 8));
    __builtin_amdgcn_s_setprio(1);
#pragma unroll
    for (int kk = 0; kk < 2; ++kk)
#pragma unroll
      for (int mi = 0; mi < 4; ++mi)
#pragma unroll
        for (int nn = 0; nn < 4; ++nn)
          acc[mi][nn] = mfma16(a[mi * 2 + kk], bCur[nn * 2 + kk], acc[mi][nn]);
    __builtin_amdgcn_s_setprio(0);

    if (kt < 8) loadB(kt + 1, bNxt);   // lands under sub-burst 2 + barrier

    // ---- sub-burst 2: mi 4..7 ----
#pragma unroll
    for (int mi = 0; mi < 4; ++mi)
#pragma unroll
      for (int kk = 0; kk < 2; ++kk)
        a[mi * 2 + kk] = *reinterpret_cast<const bfrag*>(
            As_ + (wr * 128 + 64 + mi * 16 + lr) * 64 + (((kk * 4 + lq) ^ sx) * 8));
    __builtin_amdgcn_s_setprio(1);
#pragma unroll
    for (int kk = 0; kk < 2; ++kk)
#pragma unroll
      for (int mi = 0; mi < 4; ++mi)
#pragma unroll
        for (int nn = 0; nn < 4; ++nn)
          acc[4 + mi][nn] = mfma16(a[mi * 2 + kk], bCur[nn * 2 + kk], acc[4 + mi][nn]);
    __builtin_amdgcn_s_setprio(0);
    __builtin_amdgcn_sched_barrier(0);

    if (kt < 8) {
      asm volatile("s_waitcnt vmcnt(8)" ::: "memory");  // A-stage landed; 8 b-loads in flight
      __builtin_amdgcn_sched_barrier(0);
      __builtin_amdgcn_s_barrier();
    }
  }

  // ---- epilogue: pure per-lane gate fusion (no LDS, no barriers) ----
  // Lane's unit u = (bn*4+wc)*16 + lr; acc[mi][nn][j]: nn = gate (i,f,g,o),
  // row = bm*256 + wr*128 + mi*16 + lq*4 + j.
  const float* biasn = biasc + mat * kNG + bn * 256 + wc * 64;
  const float bb0 = biasn[0 * 16 + lr];
  const float bb1 = biasn[1 * 16 + lr];
  const float bb2 = biasn[2 * 16 + lr];
  const float bb3 = biasn[3 * 16 + lr];
  const int u = (bn * 4 + wc) * 16 + lr;
  const int row0 = bm * 256 + wr * 128 + lq * 4;
#pragma unroll
  for (int mi = 0; mi < 8; ++mi) {
#pragma unroll
    for (int j = 0; j < 4; ++j) {
      const float iv = sigf(acc[mi][0][j] + bb0);
      const float fv = sigf(acc[mi][1][j] + bb1);
      const float gv = tanh_fast(acc[mi][2][j] + bb2);
      const float ov = sigf(acc[mi][3][j] + bb3);
      const int row = row0 + mi * 16 + j;
      const size_t cidx = ((size_t)cell * kB + row) * kH + u;
      const float cn = fv * cbuf[cidx] + iv * gv;
      cbuf[cidx] = cn;
      hout[cidx] = (bf16_t)(ov * tanh_fast(cn));
    }
  }
}

// ---------------- head: wave shuffle reduce ----------------

__global__ __launch_bounds__(256) void head_kernel(const bf16_t* __restrict__ hfin,
                                                   const float* __restrict__ W3,
                                                   const float* __restrict__ b3,
                                                   float* __restrict__ out) {
  const int b = blockIdx.x, t = threadIdx.x;
  const int l = t & 63, w = t >> 6;
  float acc[10];
#pragma unroll
  for (int j = 0; j < 10; ++j) acc[j] = 0.f;
  for (int k = t; k < 2048; k += 256) {
    const int cell = k >> 9, u = k & 511;
    const float hv = (float)hfin[((size_t)cell * kB + b) * kH + u];
#pragma unroll
    for (int j = 0; j < 10; ++j) acc[j] += hv * W3[j * 2048 + k];
  }
#pragma unroll
  for (int j = 0; j < 10; ++j)
#pragma unroll
    for (int o = 32; o > 0; o >>= 1) acc[j] += __shfl_down(acc[j], o, 64);
  __shared__ float wred[4][10];
  if (l == 0)
#pragma unroll
    for (int j = 0; j < 10; ++j) wred[w][j] = acc[j];
  __syncthreads();
  if (t == 0) {
    float logits[10];
#pragma unroll
    for (int j = 0; j < 10; ++j)
      logits[j] = wred[0][j] + wred[1][j] + wred[2][j] + wred[3][j] + b3[j];
    float mx = logits[0];
#pragma unroll
    for (int j = 1; j < 10; ++j) mx = fmaxf(mx, logits[j]);
    float se = 0.f;
#pragma unroll
    for (int j = 0; j < 10; ++j) se += expf(logits[j] - mx);
    const float lse = mx + logf(se);
#pragma unroll
    for (int j = 0; j < 10; ++j) out[(size_t)b * 10 + j] = logits[j] - lse;
  }
}

}  // namespace

extern "C" void kernel_launch(void* const* d_in, const int* in_sizes, int n_in,
                              void* d_out, int out_size, void* d_ws, size_t ws_size,
                              hipStream_t stream) {
  const float* x     = (const float*)d_in[0];
  const float* h0    = (const float*)d_in[1];
  const float* c0    = (const float*)d_in[2];
  const float* W1    = (const float*)d_in[3];
  const float* b1    = (const float*)d_in[4];
  const float* Wih_l = (const float*)d_in[5];
  const float* Whh_l = (const float*)d_in[6];
  const float* bih_l = (const float*)d_in[7];
  const float* bhh_l = (const float*)d_in[8];
  const float* Wih_r = (const float*)d_in[9];
  const float* Whh_r = (const float*)d_in[10];
  const float* bih_r = (const float*)d_in[11];
  const float* bhh_r = (const float*)d_in[12];
  const float* Wih_d = (const float*)d_in[13];
  const float* Whh_d = (const float*)d_in[14];
  const float* bih_d = (const float*)d_in[15];
  const float* bhh_d = (const float*)d_in[16];
  const float* W3    = (const float*)d_in[17];
  const float* b3    = (const float*)d_in[18];
  float* out = (float*)d_out;

  char* p = (char*)d_ws;
  auto take = [&](size_t bytes) {
    char* r = p;
    p += (bytes + 255) & ~(size_t)255;
    return r;
  };
  bf16_t* xb    = (bf16_t*)take((size_t)kB * kIN * 2);   // later reused as featT
  bf16_t* w1b   = (bf16_t*)take((size_t)kFS * kIN * 2);  // later reused as hbuf (2 slots)
  bf16_t* feat  = (bf16_t*)take((size_t)kB * kFS * 2);
  bf16_t* wcat2 = (bf16_t*)take((size_t)3 * 128 * 9 * 2 * 64 * 8 * 2);
  float*  biasc = (float*)take((size_t)3 * kNG * 4);
  float*  cbuf  = (float*)take((size_t)4 * kB * kH * 4);
  bf16_t* featT = xb;   // safe: gemm_feat (reads xb) precedes transpose (writes featT)
  bf16_t* hbuf  = w1b;  // safe: gemm_feat (reads w1b) precedes pack_hc
  const size_t HSZ = (size_t)4 * kB * kH;

  (void)hipFuncSetAttribute(reinterpret_cast<const void*>(&lstm_step_kernel),
                            hipFuncAttributeMaxDynamicSharedMemorySize, 65536);

  f2b4_kernel<<<(kB * kIN / 4) / 256, 256, 0, stream>>>(x, xb, kB * kIN / 4);
  f2b4_kernel<<<(kFS * kIN / 4) / 256, 256, 0, stream>>>(W1, w1b, kFS * kIN / 4);
  gemm_feat_kernel<<<dim3(1024), 256, 0, stream>>>(xb, w1b, b1, feat);
  transpose64_kernel<<<kB, 256, 0, stream>>>(feat, featT);
  {
    const int total = 3 * 128 * 9 * 2 * 64 * 8;
    pack_wcat2_kernel<<<(total + 255) / 256, 256, 0, stream>>>(
        Wih_l, Whh_l, Wih_r, Whh_r, Wih_d, Whh_d, wcat2);
  }
  pack_bias_kernel<<<(3 * kNG + 255) / 256, 256, 0, stream>>>(
      bih_l, bhh_l, bih_r, bhh_r, bih_d, bhh_d, biasc);
  pack_hc_kernel<<<(int)(HSZ / 256), 256, 0, stream>>>(h0, c0, hbuf, cbuf, (int)HSZ);

  for (int s = 0; s < 64; ++s) {
    lstm_step_kernel<<<dim3(512), 512, 65536, stream>>>(
        feat, featT, wcat2, biasc,
        hbuf + (size_t)(s & 1) * HSZ, hbuf + (size_t)((s + 1) & 1) * HSZ, cbuf, s);
  }
  head_kernel<<<kB, 256, 0, stream>>>(hbuf, W3, b3, out);
}